// Round 9
// baseline (9443.300 us; speedup 1.0000x reference)
//
#include <hip/hip_runtime.h>
#include <math.h>

// Problem constants
#define B_   64
#define S_   512
#define D_   256
#define H_   512
#define G4   2048           // 4H
#define K0   768            // D + H   (layer 0)
#define K1   1024           // H + H   (layer 1)
#define NWG  256
#define NAH  128            // WGs 0-127: layer 0 (A); 128-255: layer 1 (B)
#define NTHR 256
#define CK   64             // K-chunk staged through LDS
#define BH   32768          // B_*H_
#define NROT 4              // xbuf rotation depth (L0 reuse-distance >= 4 rounds)

// ws layout (float/uint indices)
#define OFF_GF   32         // 8 per-XCD global flags x16 -> [32,160)
#define OFF_SCL  192        // exp(efw), 256 floats
#define OFF_FLG  512        // 256 startup flags x16 -> [512,4608)
#define OFF_EPO  4608       // startup epoch replicas 8x16
#define OFF_TKT  4736       // per-XCD tickets 8x16
#define OFF_ACN  4864       // per-XCD hbar arrive counters 8x16
#define OFF_RLS  4992       // per-XCD hbar release counters 8x16
#define OFF_XCN  5120       // per-XCD stage-barrier counters 8x16
#define OFF_H0   5248       // [2][B][H] layer-0 h (parity double buffer)
#define OFF_H1   (OFF_H0 + 2*BH)
#define OFF_C0   (OFF_H1 + 2*BH)
#define OFF_C1   (OFF_C0 + BH)
#define OFF_ZEND (OFF_C1 + BH)          // init zeroes up to here
#define OFF_XBUF OFF_ZEND               // per-XCD staging: [8][NROT][2*BH]
#define XBUF_SZ  (8 * NROT * 2 * BH)
#define OFF_END  (OFF_XBUF + XBUF_SZ)   // ~9.2 MB

typedef __attribute__((ext_vector_type(4))) float f32x4;

__device__ __forceinline__ float sigm(float v) { return 1.0f / (1.0f + expf(-v)); }

// sc1 (IF$-point) relaxed atomics -- cross-XCD safe (R4/R7-proven).
#define ALD(p)   __hip_atomic_load((p), __ATOMIC_RELAXED, __HIP_MEMORY_SCOPE_AGENT)
#define AST(p,v) __hip_atomic_store((p), (v), __ATOMIC_RELAXED, __HIP_MEMORY_SCOPE_AGENT)

// Intra-XCD primitives: atomic RMWs execute at the local L2 (L0 has no atomic
// path -> can never be served stale, unlike ANY load flavor). R7-proven.
__device__ __forceinline__ void xadd_noret(unsigned* p, unsigned v) {
  asm volatile("global_atomic_add %0, %1, off\n\t"
               "s_waitcnt vmcnt(0)"
               :: "v"(p), "v"(v) : "memory");
}
__device__ __forceinline__ unsigned xadd_ret0(unsigned* p) {
  unsigned r, z = 0u;
  asm volatile("global_atomic_add %0, %1, %2, off sc0\n\t"
               "s_waitcnt vmcnt(0)"
               : "=&v"(r) : "v"(p), "v"(z) : "memory");
  return r;
}

// 2x16B agent-scope (sc1) loads for staging: IF$-fresh, fewer vmem ops.
// NOTE gfx950 asm: offset: immediate must PRECEDE cache flags (R8 compile fix).
__device__ __forceinline__ void ld2x4_sc1(const float* p, f32x4& a, f32x4& b) {
  asm volatile("global_load_dwordx4 %0, %2, off sc1\n\t"
               "global_load_dwordx4 %1, %2, off offset:16 sc1\n\t"
               "s_waitcnt vmcnt(0)"
               : "=&v"(a), "=&v"(b) : "v"(p) : "memory");
}

// Zero persistent state + precompute exp(efw). Stream-ordered each call ->
// deterministic per graph replay. Kernel-end writeback + next-kernel acquire
// publish the zeros to all L2s (R7-proven).
__global__ void lstm_init(const float* __restrict__ efw, float* __restrict__ ws) {
  int stride = gridDim.x * blockDim.x;
  for (int j = blockIdx.x * blockDim.x + threadIdx.x; j < OFF_ZEND; j += stride) {
    float v = 0.0f;
    if (j >= OFF_SCL && j < OFF_SCL + D_) v = expf(efw[j - OFF_SCL]);
    ws[j] = v;
  }
}

__launch_bounds__(NTHR, 1)
__global__ void lstm_persist(const float* __restrict__ x,
                             const float* __restrict__ W0,
                             const float* __restrict__ b0,
                             const float* __restrict__ W1,
                             const float* __restrict__ b1,
                             float* __restrict__ out,
                             float* __restrict__ ws,
                             const int stg)
{
  __shared__ float wW[K1][16];      // 64 KB   weight slice [k][col]
  __shared__ float aT[CK][68];      // 17 KB   A-chunk [k][row^swz] (R7 swizzle)
  __shared__ float pR[4][B_][20];   // 20.5 KB per-wave partials
  __shared__ float scl[D_];         // 1 KB    exp(efw)
  __shared__ int   sslot;

  const int  wg  = blockIdx.x;
  const int  tid = threadIdx.x;
  const bool isA = (wg < NAH);
  const int  u0  = (isA ? wg : wg - NAH) * 4;
  const int  K   = isA ? K0 : K1;
  const int  nch = K / CK;          // 12 (A) / 16 (B)

  float* h0 = ws + OFF_H0;
  float* h1 = ws + OFF_H1;
  float* cs = ws + (isA ? OFF_C0 : OFF_C1);
  float* xbuf = ws + OFF_XBUF;
  unsigned* gf  = (unsigned*)ws + OFF_GF;
  unsigned* epo = (unsigned*)ws + OFF_EPO;
  unsigned* flg = (unsigned*)ws + OFF_FLG;
  unsigned* tkt = (unsigned*)ws + OFF_TKT;

  // One-time: stage weight slice into LDS (plain, read-only).
  {
    const float* W = isA ? W0 : W1;
    for (int i = tid; i < K * 16; i += NTHR) {
      int k = i >> 4, cl = i & 15, g = cl >> 2, u2 = cl & 3;
      wW[k][cl] = W[(size_t)k * G4 + g * H_ + u0 + u2];
    }
  }
  for (int i = tid; i < D_; i += NTHR) scl[i] = ws[OFF_SCL + i];

  // XCD identity + slot ticket (agent-scope RMW at IF$, one-time).
  int xcc = 0, slot = 0, nx = 1;
  if (stg) {
    // s_getreg hwreg(HW_REG_XCC_ID=20, off 0, sz 32): simm = (31<<11)|20
    xcc = (int)(__builtin_amdgcn_s_getreg(63508) & 7u);
    if (tid == 0)
      sslot = (int)__hip_atomic_fetch_add(tkt + (size_t)xcc * 16, 1u,
                                          __ATOMIC_RELAXED, __HIP_MEMORY_SCOPE_AGENT);
    __syncthreads();
    slot = sslot;
  }
  unsigned* acnt = (unsigned*)ws + OFF_ACN + (size_t)xcc * 16;
  unsigned* rls  = (unsigned*)ws + OFF_RLS + (size_t)xcc * 16;
  unsigned* xcnt = (unsigned*)ws + OFF_XCN + (size_t)xcc * 16;

  // ---- startup-only global barrier (R4/R7-proven sc1 flag protocol) ----
  auto gbar = [&](unsigned tgt) {
    __syncthreads();
    if (tid == 0) AST(flg + (size_t)wg * 16, tgt);
    if (wg == 0 && tid < 64) {
      for (;;) {
        unsigned m0 = ALD(flg + (size_t)(tid       ) * 16);
        unsigned m1 = ALD(flg + (size_t)(tid +  64) * 16);
        unsigned m2 = ALD(flg + (size_t)(tid + 128) * 16);
        unsigned m3 = ALD(flg + (size_t)(tid + 192) * 16);
        if (__all(m0 >= tgt && m1 >= tgt && m2 >= tgt && m3 >= tgt)) break;
      }
      if (tid == 0) {
#pragma unroll
        for (int kq = 0; kq < 8; ++kq) AST(epo + (size_t)kq * 16, tgt);
      }
    }
    if (tid < 64) {
      while (ALD(epo + (size_t)(wg & 7) * 16) < tgt)
        __builtin_amdgcn_s_sleep(4);
    }
    __syncthreads();
  };

  // ---- hierarchical global barrier: L2 arrive + 8 sc1 flags + L2 release ----
  // Replaces 256 sc1 stores + 16K-lane sc1 spin (R7's ~6-7us) with 8 sc1
  // stores + 8-lane poll; all spinning is on local-L2 atomic counters.
  auto hbar = [&](unsigned ev) {
    __syncthreads();                  // all waves' vmcnt drained: h at IF$
    if (tid == 0) {
      xadd_noret(acnt, 1u);           // local arrive
      if (slot == 0) {                // rep: wait all local WGs
        const unsigned tgt = ev * (unsigned)nx;
        while (xadd_ret0(acnt) < tgt) __builtin_amdgcn_s_sleep(2);
      }
    }
    if (slot == 0 && tid < 64) {      // rep wave: publish + poll 8 XCD flags
      if (tid == 0) AST(gf + (size_t)xcc * 16, ev);
      unsigned v = ev;
      for (;;) {
        if (tid < 8) v = ALD(gf + (size_t)tid * 16);
        if (__all(v >= ev)) break;
        __builtin_amdgcn_s_sleep(2);
      }
      if (tid == 0) xadd_noret(rls, 1u);   // local release
    }
    if (tid == 0) {
      while (xadd_ret0(rls) < ev) __builtin_amdgcn_s_sleep(4);
    }
    __syncthreads();
  };

  // ---- XCD-local stage barrier (R7-proven) ----
  auto xbar = [&](unsigned ev) {
    __syncthreads();                  // vmcnt(0) drain: staging stores in L2
    if (tid == 0) {
      xadd_noret(xcnt, 1u);
      const unsigned tgt = ev * (unsigned)nx;
      while (xadd_ret0(xcnt) < tgt) __builtin_amdgcn_s_sleep(4);
    }
    __syncthreads();
  };

  // Pre-loop global barrier: tickets final + init zeros globally visible.
  gbar(1u);
  if (stg) nx = (int)ALD(tkt + (size_t)xcc * 16);   // residents on this XCD

  // Stager: copy {h0[q], h1[q]} (sc1, IF$-fresh) into this XCD's rot slot.
  auto stage_xcd = [&](int q, int rot) {
    for (int s = slot; s < 32; s += nx) {
      int off = s * 2048 + tid * 8;               // [0, 2*BH)
      const float* gs = (off < BH) ? ws + OFF_H0 + (size_t)q * BH + off
                                   : ws + OFF_H1 + (size_t)q * BH + (off - BH);
      f32x4 w0, w1;
      ld2x4_sc1(gs, w0, w1);
      float* dst = xbuf + ((size_t)xcc * NROT + rot) * (2 * BH) + off;
      *(f32x4*)(dst)     = w0;                    // plain: dirty in own L2
      *(f32x4*)(dst + 4) = w1;
    }
  };

  if (stg) {                // pre-stage parity 1 (zeros) into rot 3 (event 1)
    stage_xcd(1, 3);
    xbar(1u);
  }

  // GEMM-phase roles
  const int rq  = tid & 15;         // rows 4rq..4rq+3
  const int cq  = (tid >> 4) & 3;   // cols 4cq..4cq+3
  const int wv_ = tid >> 6;         // wave k-phase
  const int row_r = tid & 63;       // update-phase batch row
  const int uu    = tid >> 6;       // update-phase unit sub-index
  float bias[4];
  {
    const float* bv = isA ? b0 : b1;
#pragma unroll
    for (int g = 0; g < 4; ++g) bias[g] = bv[g * H_ + u0 + uu];
  }
  __syncthreads();

  const float *bh0 = nullptr, *bh1 = nullptr;  // per-round A-source bases

  float rg[16];
  auto stage_load = [&](int c, int t) {
    if (isA && c < 4) {                           // x part (plain, scaled)
#pragma unroll
      for (int i = 0; i < 4; ++i) {
        int s = tid + NTHR * i;
        int row = s >> 4, kk = (s & 15) << 2, gk = c * CK + kk;
        float4 v  = *(const float4*)(x + ((size_t)row * S_ + t) * D_ + gk);
        float4 sc = *(const float4*)&scl[gk];
        rg[4*i+0] = v.x * sc.x; rg[4*i+1] = v.y * sc.y;
        rg[4*i+2] = v.z * sc.z; rg[4*i+3] = v.w * sc.w;
      }
    } else {
      const float* base; int coloff;
      if (isA)         { base = bh0; coloff = c * CK - D_; }
      else if (c < 8)  { base = bh0; coloff = c * CK; }
      else             { base = bh1; coloff = c * CK - H_; }
      if (stg) {        // plain loads: L2-hit on staged lines; L0 staleness
                        // impossible (NROT=4 rotation > L0 lifetime)
#pragma unroll
        for (int i = 0; i < 4; ++i) {
          int s = tid + NTHR * i;
          int row = s >> 4, kk = (s & 15) << 2;
          float4 v = *(const float4*)(base + (size_t)row * H_ + coloff + kk);
          rg[4*i+0] = v.x; rg[4*i+1] = v.y; rg[4*i+2] = v.z; rg[4*i+3] = v.w;
        }
      } else {                                    // fallback: direct sc1 reads
#pragma unroll
        for (int i = 0; i < 4; ++i) {
          int s = tid + NTHR * i;
          int row = s >> 4, kk = (s & 15) << 2;
          const float* src = base + (size_t)row * H_ + coloff + kk;
          rg[4*i+0] = ALD(src+0); rg[4*i+1] = ALD(src+1);
          rg[4*i+2] = ALD(src+2); rg[4*i+3] = ALD(src+3);
        }
      }
    }
  };

  for (int r = 0; r <= S_; ++r) {
    const int  p   = r & 1;
    const bool act = isA ? (r < S_) : (r >= 1);
    if (act) {
      const int t = isA ? r : r - 1;
      if (stg) {        // consume the slot staged at end of round r-1
        const float* cb = xbuf + ((size_t)xcc * NROT + ((r + 3) & 3)) * (2 * BH);
        bh0 = cb; bh1 = cb + BH;
      } else {
        bh0 = h0 + (size_t)(p ^ 1) * BH; bh1 = h1 + (size_t)(p ^ 1) * BH;
      }
      float acc[4][4] = {{0.f,0.f,0.f,0.f},{0.f,0.f,0.f,0.f},
                         {0.f,0.f,0.f,0.f},{0.f,0.f,0.f,0.f}};
      stage_load(0, t);

      for (int c = 0; c < nch; ++c) {
        __syncthreads();
        // regs -> aT with row-XOR swizzle (row' = row ^ ((m&7)<<2), m = kk>>2)
#pragma unroll
        for (int i = 0; i < 4; ++i) {
          int s = tid + NTHR * i;
          int row = s >> 4, m = s & 15, kk = m << 2;
          int rw = row ^ ((m & 7) << 2);
          aT[kk+0][rw] = rg[4*i+0]; aT[kk+1][rw] = rg[4*i+1];
          aT[kk+2][rw] = rg[4*i+2]; aT[kk+3][rw] = rg[4*i+3];
        }
        if (c + 1 < nch) stage_load(c + 1, t);
        __syncthreads();
        const int kb = wv_ * 16;
#pragma unroll
        for (int kk = 0; kk < 16; ++kk) {
          const int kidx = kb + kk;
          float4 a  = *(const float4*)
              &aT[kidx][(rq << 2) ^ (((kidx >> 2) & 7) << 2)];
          float4 wv = *(const float4*)&wW[c * CK + kidx][cq << 2];
          acc[0][0] += a.x*wv.x; acc[0][1] += a.x*wv.y; acc[0][2] += a.x*wv.z; acc[0][3] += a.x*wv.w;
          acc[1][0] += a.y*wv.x; acc[1][1] += a.y*wv.y; acc[1][2] += a.y*wv.z; acc[1][3] += a.y*wv.w;
          acc[2][0] += a.z*wv.x; acc[2][1] += a.z*wv.y; acc[2][2] += a.z*wv.z; acc[2][3] += a.z*wv.w;
          acc[3][0] += a.w*wv.x; acc[3][1] += a.w*wv.y; acc[3][2] += a.w*wv.z; acc[3][3] += a.w*wv.w;
        }
      }

#pragma unroll
      for (int j = 0; j < 4; ++j) {
        pR[wv_][(rq<<2)+j][(cq<<2)+0] = acc[j][0];
        pR[wv_][(rq<<2)+j][(cq<<2)+1] = acc[j][1];
        pR[wv_][(rq<<2)+j][(cq<<2)+2] = acc[j][2];
        pR[wv_][(rq<<2)+j][(cq<<2)+3] = acc[j][3];
      }
      __syncthreads();

      float z[4];
#pragma unroll
      for (int g = 0; g < 4; ++g) {
        int cl = (g << 2) + uu;
        z[g] = pR[0][row_r][cl] + pR[1][row_r][cl]
             + pR[2][row_r][cl] + pR[3][row_r][cl] + bias[g];
      }
      const int ui = u0 + uu;
      float c_ = cs[(size_t)row_r * H_ + ui];
      float i_ = sigm(z[0]);
      float f_ = sigm(z[1] + c_) * 0.9f;          // decayed forget (DECAY=0.1)
      float g_ = tanhf(z[2]);
      float o_ = sigm(z[3]);
      float cn = f_ * c_ + i_ * g_;
      float hn = o_ * tanhf(cn);
      cs[(size_t)row_r * H_ + ui] = cn;
      float* hw = (isA ? h0 : h1) + (size_t)p * BH + (size_t)row_r * H_ + ui;
      AST(hw, hn);                                // sc1 write-through to IF$
      if (!isA) out[((size_t)row_r * S_ + t) * H_ + ui] = hn;
    }

    if (r < S_) {
      if (stg) {
        hbar((unsigned)(r + 1));                  // h[r] published at IF$
        stage_xcd(r & 1, r & 3);                  // localize into XCD L2
        xbar((unsigned)(r + 2));
      } else {
        gbar((unsigned)(r + 2));
      }
    }
  }
}

extern "C" void kernel_launch(void* const* d_in, const int* in_sizes, int n_in,
                              void* d_out, int out_size, void* d_ws, size_t ws_size,
                              hipStream_t stream) {
  const float* x   = (const float*)d_in[0];
  const float* W0  = (const float*)d_in[1];
  const float* b0  = (const float*)d_in[2];
  const float* W1  = (const float*)d_in[3];
  const float* b1  = (const float*)d_in[4];
  const float* efw = (const float*)d_in[5];
  float* out = (float*)d_out;
  float* ws  = (float*)d_ws;

  if (ws_size < (size_t)OFF_ZEND * sizeof(float)) return;
  const int stg = (ws_size >= (size_t)OFF_END * sizeof(float)) ? 1 : 0;

  lstm_init<<<256, 256, 0, stream>>>(efw, ws);
  lstm_persist<<<NWG, NTHR, 0, stream>>>(x, W0, b0, W1, b1, out, ws, stg);
}

// Round 10
// 7354.757 us; speedup vs baseline: 1.2840x; 1.2840x over previous
//
#include <hip/hip_runtime.h>
#include <math.h>

// Problem constants
#define B_   64
#define S_   512
#define D_   256
#define H_   512
#define G4   2048
#define K0   768
#define K1   1024
#define NWG  256
#define NAH  128
#define NTHR 256
#define BH   32768          // B_*H_
#define NROT 4

// ws layout (float/uint indices)
#define OFF_GF   32
#define OFF_SCL  192
#define OFF_FLG  512
#define OFF_EPO  4608
#define OFF_TKT  4736
#define OFF_ACN  4864
#define OFF_RLS  4992
#define OFF_XCN  5120
#define OFF_H0   5248
#define OFF_H1   (OFF_H0 + 2*BH)
#define OFF_C0   (OFF_H1 + 2*BH)
#define OFF_C1   (OFF_C0 + BH)
#define OFF_ZEND (OFF_C1 + BH)
#define OFF_XBUF OFF_ZEND               // per-XCD: [8][NROT] slots
#define XBUF_SZ  (8 * NROT * 2 * BH)    // floats; slot = 2BH floats = 4BH shorts (hi|lo bf16)
#define OFF_END  (OFF_XBUF + XBUF_SZ)

typedef __attribute__((ext_vector_type(4))) float f32x4;
typedef __attribute__((ext_vector_type(8))) short s16x8;

__device__ __forceinline__ float sigm(float v){ return 1.0f/(1.0f+expf(-v)); }
__device__ __forceinline__ unsigned short f2bf(float f){
  unsigned u = __builtin_bit_cast(unsigned, f);
  return (unsigned short)((u + 0x7FFFu + ((u>>16)&1u)) >> 16);   // RNE
}
__device__ __forceinline__ float bf2f(unsigned short s){
  return __builtin_bit_cast(float, ((unsigned)s) << 16);
}
__device__ __forceinline__ void split8(const float* v, s16x8& h, s16x8& l){
#pragma unroll
  for (int e = 0; e < 8; ++e){
    unsigned short hs = f2bf(v[e]);
    h[e] = (short)hs;
    l[e] = (short)f2bf(v[e] - bf2f(hs));
  }
}

// sc1 (IF$-point) relaxed atomics -- cross-XCD safe (R4/R7-proven).
#define ALD(p)   __hip_atomic_load((p), __ATOMIC_RELAXED, __HIP_MEMORY_SCOPE_AGENT)
#define AST(p,v) __hip_atomic_store((p), (v), __ATOMIC_RELAXED, __HIP_MEMORY_SCOPE_AGENT)

// Intra-XCD: atomic RMWs execute at local L2 (L0 has no atomic path -> never
// stale; any LOAD flavor can be L0-stale -> R5/R6 deadlocks). R7-proven.
__device__ __forceinline__ void xadd_noret(unsigned* p, unsigned v){
  asm volatile("global_atomic_add %0, %1, off\n\ts_waitcnt vmcnt(0)"
               :: "v"(p), "v"(v) : "memory");
}
__device__ __forceinline__ unsigned xadd_ret0(unsigned* p){
  unsigned r, z = 0u;
  asm volatile("global_atomic_add %0, %1, %2, off sc0\n\ts_waitcnt vmcnt(0)"
               : "=&v"(r) : "v"(p), "v"(z) : "memory");
  return r;
}
// 2x16B sc1 loads (IF$-fresh). gfx950: offset: must precede cache flags.
__device__ __forceinline__ void ld2x4_sc1(const float* p, f32x4& a, f32x4& b){
  asm volatile("global_load_dwordx4 %0, %2, off sc1\n\t"
               "global_load_dwordx4 %1, %2, off offset:16 sc1\n\t"
               "s_waitcnt vmcnt(0)"
               : "=&v"(a), "=&v"(b) : "v"(p) : "memory");
}

__global__ void lstm_init(const float* __restrict__ efw, float* __restrict__ ws){
  int stride = gridDim.x * blockDim.x;
  for (int j = blockIdx.x * blockDim.x + threadIdx.x; j < OFF_ZEND; j += stride){
    float v = 0.0f;
    if (j >= OFF_SCL && j < OFF_SCL + D_) v = expf(efw[j - OFF_SCL]);
    ws[j] = v;
  }
}

__launch_bounds__(NTHR, 1)
__global__ void lstm_persist(const float* __restrict__ x,
                             const float* __restrict__ W0,
                             const float* __restrict__ b0,
                             const float* __restrict__ W1,
                             const float* __restrict__ b1,
                             float* __restrict__ out,
                             float* __restrict__ ws)
{
  // Fragment-linear LDS (lane l reads/writes byte l*16 of a 1KB block):
  __shared__ short wfH[32*64*8];    // 32KB  W hi frags [ki][lane][8]
  __shared__ short wfL[32*64*8];    // 32KB  W lo frags
  __shared__ short afH[16*64*8];    // 16KB  A hi frags [rb*4+ki][lane][8] (CK=128)
  __shared__ short afL[16*64*8];    // 16KB  A lo frags
  __shared__ float zB[64*17];       // 4.3KB gate exchange (pad 17)
  __shared__ float scl[D_];         // 1KB   exp(efw)
  __shared__ int   sslot;           // total ~101.6KB -> 1 WG/CU

  const int  wg  = blockIdx.x;
  const int  tid = threadIdx.x;
  const bool isA = (wg < NAH);
  const int  u0  = (isA ? wg : wg - NAH) * 4;
  const int  KI  = isA ? 24 : 32;    // K/32
  const int  nch = isA ? 6 : 8;      // K/128
  const int  lane = tid & 63;
  const int  wv_  = tid >> 6;        // wave = row-block rb

  float* h0 = ws + OFF_H0;
  float* h1 = ws + OFF_H1;
  float* cs = ws + (isA ? OFF_C0 : OFF_C1);
  short* XB = (short*)(ws + OFF_XBUF);
  unsigned* gf  = (unsigned*)ws + OFF_GF;
  unsigned* epo = (unsigned*)ws + OFF_EPO;
  unsigned* flg = (unsigned*)ws + OFF_FLG;
  unsigned* tkt = (unsigned*)ws + OFF_TKT;

  // One-time: W -> split-bf16 fragments (B-frag: col=l%16, k=ki*32+(l/16)*8+e).
  {
    const float* W = isA ? W0 : W1;
    for (int f = tid; f < KI*64; f += NTHR){
      int ki = f >> 6, ln = f & 63;
      int col = ln & 15, g = col >> 2, u2 = col & 3;
      int kb = ki*32 + ((ln >> 4) << 3);
      const float* wp = W + (size_t)kb * G4 + g * H_ + u0 + u2;
      s16x8 hh, ll;
#pragma unroll
      for (int e = 0; e < 8; ++e){
        float w = wp[(size_t)e * G4];
        unsigned short hs = f2bf(w);
        hh[e] = (short)hs;
        ll[e] = (short)f2bf(w - bf2f(hs));
      }
      *(s16x8*)&wfH[(size_t)f * 8] = hh;
      *(s16x8*)&wfL[(size_t)f * 8] = ll;
    }
  }
  for (int i = tid; i < D_; i += NTHR) scl[i] = ws[OFF_SCL + i];

  // XCD identity + slot ticket (agent RMW at IF$, one-time).
  int xcc, slot, nx = 1;
  {
    xcc = (int)(__builtin_amdgcn_s_getreg(63508) & 7u);  // HW_REG_XCC_ID
    if (tid == 0)
      sslot = (int)__hip_atomic_fetch_add(tkt + (size_t)xcc*16, 1u,
                 __ATOMIC_RELAXED, __HIP_MEMORY_SCOPE_AGENT);
    __syncthreads();
    slot = sslot;
  }
  unsigned* acnt = (unsigned*)ws + OFF_ACN + (size_t)xcc*16;
  unsigned* rls  = (unsigned*)ws + OFF_RLS + (size_t)xcc*16;
  unsigned* xcnt = (unsigned*)ws + OFF_XCN + (size_t)xcc*16;

  // ---- startup-only global barrier (R4-proven sc1 flags) ----
  auto gbar = [&](unsigned tgt){
    __syncthreads();
    if (tid == 0) AST(flg + (size_t)wg * 16, tgt);
    if (wg == 0 && tid < 64){
      for (;;){
        unsigned m0 = ALD(flg + (size_t)(tid       ) * 16);
        unsigned m1 = ALD(flg + (size_t)(tid +  64) * 16);
        unsigned m2 = ALD(flg + (size_t)(tid + 128) * 16);
        unsigned m3 = ALD(flg + (size_t)(tid + 192) * 16);
        if (__all(m0 >= tgt && m1 >= tgt && m2 >= tgt && m3 >= tgt)) break;
      }
      if (tid == 0){
#pragma unroll
        for (int kq = 0; kq < 8; ++kq) AST(epo + (size_t)kq * 16, tgt);
      }
    }
    if (tid < 64){
      while (ALD(epo + (size_t)(wg & 7) * 16) < tgt)
        __builtin_amdgcn_s_sleep(4);
    }
    __syncthreads();
  };

  // ---- hierarchical global barrier (R9, equivalent cost to gbar) ----
  auto hbar = [&](unsigned ev){
    __syncthreads();
    if (tid == 0){
      xadd_noret(acnt, 1u);
      if (slot == 0){
        const unsigned tgt = ev * (unsigned)nx;
        while (xadd_ret0(acnt) < tgt) __builtin_amdgcn_s_sleep(2);
      }
    }
    if (slot == 0 && tid < 64){
      if (tid == 0) AST(gf + (size_t)xcc * 16, ev);
      unsigned v = ev;
      for (;;){
        if (tid < 8) v = ALD(gf + (size_t)tid * 16);
        if (__all(v >= ev)) break;
        __builtin_amdgcn_s_sleep(2);
      }
      if (tid == 0) xadd_noret(rls, 1u);
    }
    if (tid == 0){
      while (xadd_ret0(rls) < ev) __builtin_amdgcn_s_sleep(4);
    }
    __syncthreads();
  };

  // ---- XCD-local stage barrier (R7-proven) ----
  auto xbar = [&](unsigned ev){
    __syncthreads();
    if (tid == 0){
      xadd_noret(xcnt, 1u);
      const unsigned tgt = ev * (unsigned)nx;
      while (xadd_ret0(xcnt) < tgt) __builtin_amdgcn_s_sleep(4);
    }
    __syncthreads();
  };

  gbar(1u);
  nx = (int)ALD(tkt + (size_t)xcc * 16);

  // Stager: h (fp32, IF$) -> XCD rot slot as split-bf16 [hi(2BH)|lo(2BH)] shorts.
  // Conversion happens ONCE per XCD here (was 32x redundant per-WG in R9 design).
  auto stage_xcd = [&](int q, int rot){
    short* sbw = XB + ((size_t)(xcc * NROT + rot)) * (4 * BH);
    for (int s = slot; s < 32; s += nx){
      int off = s * 2048 + tid * 8;
      const float* gs = (off < BH) ? ws + OFF_H0 + (size_t)q * BH + off
                                   : ws + OFF_H1 + (size_t)q * BH + (off - BH);
      f32x4 a, b; ld2x4_sc1(gs, a, b);
      float v[8] = {a[0], a[1], a[2], a[3], b[0], b[1], b[2], b[3]};
      s16x8 hh, ll; split8(v, hh, ll);
      *(s16x8*)(sbw + off)          = hh;   // plain: dirty in own L2
      *(s16x8*)(sbw + 2*BH + off)   = ll;
    }
  };

  stage_xcd(1, 3);        // pre-stage parity-1 zeros into rot 3
  xbar(1u);

  // update-phase roles + bias
  const int row_r = tid & 63;
  const int uu    = tid >> 6;
  float bias[4];
  {
    const float* bv = isA ? b0 : b1;
#pragma unroll
    for (int g = 0; g < 4; ++g) bias[g] = bv[g * H_ + u0 + uu];
  }
  __syncthreads();

  const short* sb = nullptr;      // per-round xbuf slot base
  s16x8 rh[4], rl[4];             // prefetched frags (static idx only)
  const int r16 = tid & 15, ksl = (tid >> 4) & 3, kiq = tid >> 6;

  // Load chunk c (CK=128) into regs as hi/lo frags. Thread -> frag(rb=j,
  // ki=kiq, lane: row%16=r16, kslice=ksl): 8 elems k = c*128+kiq*32+ksl*8.
  auto loadregs = [&](int c, int t){
    const int kk = c * 128 + kiq * 32 + ksl * 8;
#pragma unroll
    for (int j = 0; j < 4; ++j){
      const int row = 16 * j + r16;
      if (isA && kk < 256){                       // x part (scaled) -> split here
        const float* xp = x + ((size_t)row * S_ + t) * D_ + kk;
        float4 v0 = *(const float4*)xp;
        float4 v1 = *(const float4*)(xp + 4);
        float4 s0 = *(const float4*)&scl[kk];
        float4 s1 = *(const float4*)&scl[kk + 4];
        float v[8] = {v0.x*s0.x, v0.y*s0.y, v0.z*s0.z, v0.w*s0.w,
                      v1.x*s1.x, v1.y*s1.y, v1.z*s1.z, v1.w*s1.w};
        split8(v, rh[j], rl[j]);
      } else {                                    // h: pre-split bf16 in xbuf
        const short* hp;
        if (isA)           hp = sb + (size_t)row * H_ + (kk - 256);       // h0
        else if (kk < 512) hp = sb + (size_t)row * H_ + kk;               // h0
        else               hp = sb + BH + (size_t)row * H_ + (kk - 512);  // h1
        rh[j] = *(const s16x8*)hp;
        rl[j] = *(const s16x8*)(hp + 2 * BH);
      }
    }
  };

  for (int r = 0; r <= S_; ++r){
    const bool act = isA ? (r < S_) : (r >= 1);
    if (act){
      const int t = isA ? r : r - 1;
      sb = XB + ((size_t)(xcc * NROT + ((r + 3) & 3))) * (4 * BH);
      f32x4 aHH = {0.f,0.f,0.f,0.f}, aHL = aHH, aLH = aHH;  // 3 indep chains
      loadregs(0, t);

      for (int c = 0; c < nch; ++c){
        __syncthreads();                          // afrag free
#pragma unroll
        for (int j = 0; j < 4; ++j){              // conflict-free linear writes
          int fs = ((j * 4 + kiq) * 64 + lane) * 8;
          *(s16x8*)&afH[fs] = rh[j];
          *(s16x8*)&afL[fs] = rl[j];
        }
        if (c + 1 < nch) loadregs(c + 1, t);      // overlap next-chunk loads
        __syncthreads();                          // afrag ready
#pragma unroll
        for (int ki = 0; ki < 4; ++ki){
          int as  = ((wv_ * 4 + ki) * 64 + lane) * 8;
          int wsl = ((c * 4 + ki) * 64 + lane) * 8;
          s16x8 ah = *(const s16x8*)&afH[as];
          s16x8 al = *(const s16x8*)&afL[as];
          s16x8 wh = *(const s16x8*)&wfH[wsl];
          s16x8 wl = *(const s16x8*)&wfL[wsl];
          aHH = __builtin_amdgcn_mfma_f32_16x16x32_bf16(ah, wh, aHH, 0, 0, 0);
          aHL = __builtin_amdgcn_mfma_f32_16x16x32_bf16(ah, wl, aHL, 0, 0, 0);
          aLH = __builtin_amdgcn_mfma_f32_16x16x32_bf16(al, wh, aLH, 0, 0, 0);
        }
      }

      // C-frag (col=lane&15, row=(lane>>4)*4+reg; m89-verified) -> zB
      f32x4 accs = (aHH + aHL) + aLH;
#pragma unroll
      for (int reg = 0; reg < 4; ++reg){
        int row = 16 * wv_ + ((lane >> 4) << 2) + reg;
        zB[row * 17 + (lane & 15)] = accs[reg];
      }
      __syncthreads();
      {
        float z[4];
#pragma unroll
        for (int g = 0; g < 4; ++g) z[g] = zB[row_r * 17 + g * 4 + uu] + bias[g];
        const int ui = u0 + uu;
        float c_ = cs[(size_t)row_r * H_ + ui];
        float i_ = sigm(z[0]);
        float f_ = sigm(z[1] + c_) * 0.9f;        // decayed forget (DECAY=0.1)
        float g_ = tanhf(z[2]);
        float o_ = sigm(z[3]);
        float cn = f_ * c_ + i_ * g_;
        float hn = o_ * tanhf(cn);
        cs[(size_t)row_r * H_ + ui] = cn;
        float* hw = (isA ? h0 : h1) + (size_t)(r & 1) * BH + (size_t)row_r * H_ + ui;
        AST(hw, hn);                              // sc1 write-through to IF$
        if (!isA) out[((size_t)row_r * S_ + t) * H_ + ui] = hn;
      }
    }

    if (r < S_){
      hbar((unsigned)(r + 1));                    // h[r] published at IF$
      stage_xcd(r & 1, r & 3);                    // localize + split into XCD L2
      xbar((unsigned)(r + 2));
    }
  }
}

extern "C" void kernel_launch(void* const* d_in, const int* in_sizes, int n_in,
                              void* d_out, int out_size, void* d_ws, size_t ws_size,
                              hipStream_t stream){
  const float* x   = (const float*)d_in[0];
  const float* W0  = (const float*)d_in[1];
  const float* b0  = (const float*)d_in[2];
  const float* W1  = (const float*)d_in[3];
  const float* b1  = (const float*)d_in[4];
  const float* efw = (const float*)d_in[5];
  float* out = (float*)d_out;
  float* ws  = (float*)d_ws;

  if (ws_size < (size_t)OFF_END * sizeof(float)) return;  // ~9.2 MB scratch

  lstm_init<<<256, 256, 0, stream>>>(efw, ws);
  lstm_persist<<<NWG, NTHR, 0, stream>>>(x, W0, b0, W1, b1, out, ws);
}

// Round 12
// 6918.282 us; speedup vs baseline: 1.3650x; 1.0631x over previous
//
#include <hip/hip_runtime.h>
#include <math.h>

// Problem constants
#define B_   64
#define S_   512
#define D_   256
#define H_   512
#define G4   2048
#define K0   768
#define K1   1024
#define NWG  256
#define NAH  128
#define NTHR 256
#define BH   32768          // B_*H_
#define NROT 4

// ws layout (float/uint indices)
#define OFF_SCL  192
#define OFF_FLG  512        // 256 startup-gbar flags x16
#define OFF_EPO  4608
#define OFF_TKT  4736
#define OFF_XCN  5120       // per-XCD xbar counters 8x16
#define OFF_PFL  5248       // 256 producer round-tag flags x16 -> [5248,9344)
#define OFF_H0   9344
#define OFF_H1   (OFF_H0 + 2*BH)
#define OFF_C0   (OFF_H1 + 2*BH)
#define OFF_C1   (OFF_C0 + BH)
#define OFF_ZEND (OFF_C1 + BH)
#define OFF_XBUF OFF_ZEND               // per-XCD: [8][NROT] slots of 4BH shorts
#define XBUF_SZ  (8 * NROT * 2 * BH)    // floats
#define OFF_END  (OFF_XBUF + XBUF_SZ)

typedef __attribute__((ext_vector_type(4))) float f32x4;
typedef __attribute__((ext_vector_type(8))) short s16x8;
typedef __attribute__((ext_vector_type(4))) short s16x4;

__device__ __forceinline__ float sigm(float v){ return 1.0f/(1.0f+expf(-v)); }
__device__ __forceinline__ unsigned short f2bf(float f){
  unsigned u = __builtin_bit_cast(unsigned, f);
  return (unsigned short)((u + 0x7FFFu + ((u>>16)&1u)) >> 16);   // RNE
}
__device__ __forceinline__ float bf2f(unsigned short s){
  return __builtin_bit_cast(float, ((unsigned)s) << 16);
}
__device__ __forceinline__ void split8(const float* v, s16x8& h, s16x8& l){
#pragma unroll
  for (int e = 0; e < 8; ++e){
    unsigned short hs = f2bf(v[e]);
    h[e] = (short)hs;
    l[e] = (short)f2bf(v[e] - bf2f(hs));
  }
}
__device__ __forceinline__ void split4(const f32x4& v, s16x4& h, s16x4& l){
#pragma unroll
  for (int e = 0; e < 4; ++e){
    unsigned short hs = f2bf(v[e]);
    h[e] = (short)hs;
    l[e] = (short)f2bf(v[e] - bf2f(hs));
  }
}

// sc1 (IF$-point) relaxed atomics -- cross-XCD safe (R4/R7-proven).
#define ALD(p)   __hip_atomic_load((p), __ATOMIC_RELAXED, __HIP_MEMORY_SCOPE_AGENT)
#define AST(p,v) __hip_atomic_store((p), (v), __ATOMIC_RELAXED, __HIP_MEMORY_SCOPE_AGENT)

// Intra-XCD: atomic RMWs execute at local L2 (L0 has no atomic path). R7-proven.
__device__ __forceinline__ void xadd_noret(unsigned* p, unsigned v){
  asm volatile("global_atomic_add %0, %1, off\n\ts_waitcnt vmcnt(0)"
               :: "v"(p), "v"(v) : "memory");
}
__device__ __forceinline__ unsigned xadd_ret0(unsigned* p){
  unsigned r, z = 0u;
  asm volatile("global_atomic_add %0, %1, %2, off sc0\n\ts_waitcnt vmcnt(0)"
               : "=&v"(r) : "v"(p), "v"(z) : "memory");
  return r;
}
// h publication: sc1 atomic swap EXECUTES AT the IF$ -> vmcnt ack == globally
// visible. Plain sc1 stores ack before IF$ visibility (R11's race: stager saw
// the flag ~100ns after post and read stale h; full-barrier rounds R4/R7/R10
// had us of slack masking this).
__device__ __forceinline__ void hpub_sc1(float* p, float v){
  unsigned b = __builtin_bit_cast(unsigned, v);
  asm volatile("global_atomic_swap %0, %1, off sc1\n\ts_waitcnt vmcnt(0)"
               :: "v"(p), "v"(b) : "memory");
}
// two 16B sc1 loads at independent addresses (IF$-fresh).
__device__ __forceinline__ void ld_pair_sc1(const float* p0, const float* p1,
                                            f32x4& a, f32x4& b){
  asm volatile("global_load_dwordx4 %0, %2, off sc1\n\t"
               "global_load_dwordx4 %1, %3, off sc1\n\t"
               "s_waitcnt vmcnt(0)"
               : "=&v"(a), "=&v"(b) : "v"(p0), "v"(p1) : "memory");
}

__global__ void lstm_init(const float* __restrict__ efw, float* __restrict__ ws){
  int stride = gridDim.x * blockDim.x;
  for (int j = blockIdx.x * blockDim.x + threadIdx.x; j < OFF_ZEND; j += stride){
    float v = 0.0f;
    if (j >= OFF_SCL && j < OFF_SCL + D_) v = expf(efw[j - OFF_SCL]);
    ws[j] = v;
  }
}

__launch_bounds__(NTHR, 1)
__global__ void lstm_persist(const float* __restrict__ x,
                             const float* __restrict__ W0,
                             const float* __restrict__ b0,
                             const float* __restrict__ W1,
                             const float* __restrict__ b1,
                             float* __restrict__ out,
                             float* __restrict__ ws)
{
  // Fragment-linear LDS (lane l touches byte l*16 of each 1KB block):
  __shared__ short wfH[32*64*8];    // 32KB  W hi frags
  __shared__ short wfL[32*64*8];    // 32KB  W lo frags
  __shared__ short afH[16*64*8];    // 16KB  A hi frags (CK=128)
  __shared__ short afL[16*64*8];    // 16KB  A lo frags
  __shared__ float zB[64*17];       // 4.3KB gate exchange
  __shared__ float scl[D_];         // 1KB   exp(efw)
  __shared__ int   sslot;           // ~101.6KB -> 1 WG/CU

  const int  wg  = blockIdx.x;
  const int  tid = threadIdx.x;
  const bool isA = (wg < NAH);
  const int  u0  = (isA ? wg : wg - NAH) * 4;
  const int  KI  = isA ? 24 : 32;
  const int  nch = isA ? 6 : 8;
  const int  lane = tid & 63;
  const int  wv_  = tid >> 6;

  float* h0 = ws + OFF_H0;
  float* h1 = ws + OFF_H1;
  float* cs = ws + (isA ? OFF_C0 : OFF_C1);
  short* XB = (short*)(ws + OFF_XBUF);
  unsigned* epo = (unsigned*)ws + OFF_EPO;
  unsigned* flg = (unsigned*)ws + OFF_FLG;
  unsigned* tkt = (unsigned*)ws + OFF_TKT;
  unsigned* pfl = (unsigned*)ws + OFF_PFL;

  // One-time: W -> split-bf16 fragments (B-frag: col=l%16, k=ki*32+(l/16)*8+e).
  {
    const float* W = isA ? W0 : W1;
    for (int f = tid; f < KI*64; f += NTHR){
      int ki = f >> 6, ln = f & 63;
      int col = ln & 15, g = col >> 2, u2 = col & 3;
      int kb = ki*32 + ((ln >> 4) << 3);
      const float* wp = W + (size_t)kb * G4 + g * H_ + u0 + u2;
      s16x8 hh, ll;
#pragma unroll
      for (int e = 0; e < 8; ++e){
        float w = wp[(size_t)e * G4];
        unsigned short hs = f2bf(w);
        hh[e] = (short)hs;
        ll[e] = (short)f2bf(w - bf2f(hs));
      }
      *(s16x8*)&wfH[(size_t)f * 8] = hh;
      *(s16x8*)&wfL[(size_t)f * 8] = ll;
    }
  }
  for (int i = tid; i < D_; i += NTHR) scl[i] = ws[OFF_SCL + i];

  // XCD identity + slot ticket (agent RMW at IF$, one-time).
  int xcc, slot, nx = 1;
  {
    xcc = (int)(__builtin_amdgcn_s_getreg(63508) & 7u);  // HW_REG_XCC_ID
    if (tid == 0)
      sslot = (int)__hip_atomic_fetch_add(tkt + (size_t)xcc*16, 1u,
                 __ATOMIC_RELAXED, __HIP_MEMORY_SCOPE_AGENT);
    __syncthreads();
    slot = sslot;
  }
  unsigned* xcnt = (unsigned*)ws + OFF_XCN + (size_t)xcc*16;

  // ---- startup-only global barrier (R4-proven sc1 flags, tag 1) ----
  auto gbar = [&](unsigned tgt){
    __syncthreads();
    if (tid == 0) AST(flg + (size_t)wg * 16, tgt);
    if (wg == 0 && tid < 64){
      for (;;){
        unsigned m0 = ALD(flg + (size_t)(tid       ) * 16);
        unsigned m1 = ALD(flg + (size_t)(tid +  64) * 16);
        unsigned m2 = ALD(flg + (size_t)(tid + 128) * 16);
        unsigned m3 = ALD(flg + (size_t)(tid + 192) * 16);
        if (__all(m0 >= tgt && m1 >= tgt && m2 >= tgt && m3 >= tgt)) break;
      }
      if (tid == 0){
#pragma unroll
        for (int kq = 0; kq < 8; ++kq) AST(epo + (size_t)kq * 16, tgt);
      }
    }
    if (tid < 64){
      while (ALD(epo + (size_t)(wg & 7) * 16) < tgt)
        __builtin_amdgcn_s_sleep(4);
    }
    __syncthreads();
  };

  // ---- XCD-local barrier (R7-proven L2 atomic counter) ----
  auto xbar = [&](unsigned ev){
    __syncthreads();                  // staging stores drained into local L2
    if (tid == 0){
      xadd_noret(xcnt, 1u);
      const unsigned tgt = ev * (unsigned)nx;
      while (xadd_ret0(xcnt) < tgt) __builtin_amdgcn_s_sleep(2);
    }
    __syncthreads();
  };

  gbar(1u);                           // tickets final + init zeros visible
  nx = (int)ALD(tkt + (size_t)xcc * 16);

  // Dataflow stager: column-group g of {h0[q],h1[q]} depends on exactly 8
  // producers (A:4g..4g+3, B:128+4g..+3). Poll their round-tag flags (sc1),
  // then pull the stripe from IF$ (data guaranteed there: h published via
  // sc1 atomic swap BEFORE flag post), split, store to local rot slot.
  const int srow = tid >> 2, sc4 = (tid & 3) << 2;
  auto stage_round = [&](int q, int rot, unsigned tag){
    short* sbw = XB + ((size_t)(xcc * NROT + rot)) * (4 * (size_t)BH);
    for (int g = slot; g < 32; g += nx){
      int fidx = (lane < 4) ? (4*g + lane)
               : (lane < 8 ? 128 + 4*g + (lane - 4) : -1);
      unsigned v = tag;
      for (;;){
        if (fidx >= 0) v = ALD(pfl + (size_t)fidx * 16);
        if (__all(v >= tag)) break;
        __builtin_amdgcn_s_sleep(1);
      }
      const int col = 16*g + sc4;
      const float* g0 = ws + OFF_H0 + (size_t)q * BH + (size_t)srow * H_ + col;
      const float* g1 = ws + OFF_H1 + (size_t)q * BH + (size_t)srow * H_ + col;
      f32x4 a, b; ld_pair_sc1(g0, g1, a, b);
      s16x4 h0h, h0l, h1h, h1l;
      split4(a, h0h, h0l); split4(b, h1h, h1l);
      size_t o = (size_t)srow * H_ + col;
      *(s16x4*)(sbw + o)                  = h0h;   // h0 hi  [0,BH)
      *(s16x4*)(sbw + (size_t)BH + o)     = h1h;   // h1 hi  [BH,2BH)
      *(s16x4*)(sbw + 2*(size_t)BH + o)   = h0l;   // h0 lo  [2BH,3BH)
      *(s16x4*)(sbw + 3*(size_t)BH + o)   = h1l;   // h1 lo  [3BH,4BH)
    }
  };

  stage_round(1, 3, 0u);              // pre-stage parity-1 zeros (tag 0: no wait)
  xbar(1u);

  // update-phase roles + bias
  const int row_r = tid & 63;
  const int uu    = tid >> 6;
  float bias[4];
  {
    const float* bv = isA ? b0 : b1;
#pragma unroll
    for (int g = 0; g < 4; ++g) bias[g] = bv[g * H_ + u0 + uu];
  }
  __syncthreads();

  const short* sb = nullptr;
  s16x8 rh[4], rl[4];
  const int r16 = tid & 15, ksl = (tid >> 4) & 3, kiq = tid >> 6;

  auto loadregs = [&](int c, int t){
    const int kk = c * 128 + kiq * 32 + ksl * 8;
#pragma unroll
    for (int j = 0; j < 4; ++j){
      const int row = 16 * j + r16;
      if (isA && kk < 256){                       // x part (scaled), split here
        const float* xp = x + ((size_t)row * S_ + t) * D_ + kk;
        float4 v0 = *(const float4*)xp;
        float4 v1 = *(const float4*)(xp + 4);
        float4 s0 = *(const float4*)&scl[kk];
        float4 s1 = *(const float4*)&scl[kk + 4];
        float v[8] = {v0.x*s0.x, v0.y*s0.y, v0.z*s0.z, v0.w*s0.w,
                      v1.x*s1.x, v1.y*s1.y, v1.z*s1.z, v1.w*s1.w};
        split8(v, rh[j], rl[j]);
      } else {                                    // h: pre-split bf16 in xbuf
        const short* hp;
        if (isA)           hp = sb + (size_t)row * H_ + (kk - 256);
        else if (kk < 512) hp = sb + (size_t)row * H_ + kk;
        else               hp = sb + BH + (size_t)row * H_ + (kk - 512);
        rh[j] = *(const s16x8*)hp;
        rl[j] = *(const s16x8*)(hp + 2 * BH);
      }
    }
  };

  for (int r = 0; r <= S_; ++r){
    const bool act = isA ? (r < S_) : (r >= 1);
    if (act){
      const int t = isA ? r : r - 1;
      sb = XB + ((size_t)(xcc * NROT + ((r + 3) & 3))) * (4 * (size_t)BH);
      f32x4 aHH = {0.f,0.f,0.f,0.f}, aHL = aHH, aLH = aHH;
      loadregs(0, t);

      for (int c = 0; c < nch; ++c){
        __syncthreads();
#pragma unroll
        for (int j = 0; j < 4; ++j){
          int fs = ((j * 4 + kiq) * 64 + lane) * 8;
          *(s16x8*)&afH[fs] = rh[j];
          *(s16x8*)&afL[fs] = rl[j];
        }
        if (c + 1 < nch) loadregs(c + 1, t);
        __syncthreads();
#pragma unroll
        for (int ki = 0; ki < 4; ++ki){
          int as  = ((wv_ * 4 + ki) * 64 + lane) * 8;
          int wsl = ((c * 4 + ki) * 64 + lane) * 8;
          s16x8 ah = *(const s16x8*)&afH[as];
          s16x8 al = *(const s16x8*)&afL[as];
          s16x8 wh = *(const s16x8*)&wfH[wsl];
          s16x8 wl = *(const s16x8*)&wfL[wsl];
          aHH = __builtin_amdgcn_mfma_f32_16x16x32_bf16(ah, wh, aHH, 0, 0, 0);
          aHL = __builtin_amdgcn_mfma_f32_16x16x32_bf16(ah, wl, aHL, 0, 0, 0);
          aLH = __builtin_amdgcn_mfma_f32_16x16x32_bf16(al, wh, aLH, 0, 0, 0);
        }
      }

      // C-frag (col=lane&15, row=(lane>>4)*4+reg; m89-verified) -> zB
      f32x4 accs = (aHH + aHL) + aLH;
#pragma unroll
      for (int reg = 0; reg < 4; ++reg){
        int row = 16 * wv_ + ((lane >> 4) << 2) + reg;
        zB[row * 17 + (lane & 15)] = accs[reg];
      }
      __syncthreads();
      {
        float z[4];
#pragma unroll
        for (int g = 0; g < 4; ++g) z[g] = zB[row_r * 17 + g * 4 + uu] + bias[g];
        const int ui = u0 + uu;
        float c_ = cs[(size_t)row_r * H_ + ui];
        float i_ = sigm(z[0]);
        float f_ = sigm(z[1] + c_) * 0.9f;        // decayed forget (DECAY=0.1)
        float g_ = tanhf(z[2]);
        float o_ = sigm(z[3]);
        float cn = f_ * c_ + i_ * g_;
        float hn = o_ * tanhf(cn);
        cs[(size_t)row_r * H_ + ui] = cn;
        if (!isA) out[((size_t)row_r * S_ + t) * H_ + ui] = hn;
        float* hw = (isA ? h0 : h1) + (size_t)(r & 1) * BH + (size_t)row_r * H_ + ui;
        hpub_sc1(hw, hn);              // atomic swap: visible at IF$ at ack
      }
    }

    if (r < S_){
      __syncthreads();                  // all waves' h-swaps acked AT the IF$
      if (tid == 0) AST(pfl + (size_t)wg * 16, (unsigned)(r + 2));  // publish
      stage_round(r & 1, r & 3, (unsigned)(r + 2));  // pull deps as they land
      xbar((unsigned)(r + 2));                       // local release
    }
  }
}

extern "C" void kernel_launch(void* const* d_in, const int* in_sizes, int n_in,
                              void* d_out, int out_size, void* d_ws, size_t ws_size,
                              hipStream_t stream){
  const float* x   = (const float*)d_in[0];
  const float* W0  = (const float*)d_in[1];
  const float* b0  = (const float*)d_in[2];
  const float* W1  = (const float*)d_in[3];
  const float* b1  = (const float*)d_in[4];
  const float* efw = (const float*)d_in[5];
  float* out = (float*)d_out;
  float* ws  = (float*)d_ws;

  if (ws_size < (size_t)OFF_END * sizeof(float)) return;  // ~9.2 MB scratch

  lstm_init<<<256, 256, 0, stream>>>(efw, ws);
  lstm_persist<<<NWG, NTHR, 0, stream>>>(x, W0, b0, W1, b1, out, ws);
}